// Round 2
// baseline (98.641 us; speedup 1.0000x reference)
//
#include <hip/hip_runtime.h>

// Problem constants (match reference)
#define HH 256
#define WW 512
#define NB 128
#define N_STUFF 11
#define N_SEG 19

constexpr int    W4          = WW / 4;                     // 128 float4 groups per row
constexpr int    STUFF_N4    = N_STUFF * HH * W4;          // 360448 float4 groups
constexpr size_t STUFF_BYTES = (size_t)STUFF_N4 * 16;      // 5,898,240
constexpr size_t INST_BYTES  = (size_t)NB * HH * WW * 4;   // 67,108,864
constexpr int    COPY_STRIDE = STUFF_N4 / 4;               // 90112 (exact)

// Output 0: copy first 11 channels. 4 coalesced float4 per thread,
// stride-COPY_STRIDE so each load/store instruction stays contiguous per wave.
__global__ __launch_bounds__(256)
void copy_stuff_kernel(const float4* __restrict__ in, float4* __restrict__ out)
{
    const int i = blockIdx.x * 256 + threadIdx.x;
    #pragma unroll
    for (int k = 0; k < 4; ++k) {
        out[i + k * COPY_STRIDE] = in[i + k * COPY_STRIDE];
    }
}

// Output 1 interiors: one blockIdx.x per box, blockIdx.y slices rows.
// Only touches pixels inside the (clamped) box; the rest of the instance
// plane was already zeroed by the memset.
__global__ __launch_bounds__(256)
void box_fill_kernel(const int* __restrict__ cls,
                     const float* __restrict__ seg,
                     const float* __restrict__ boxes,
                     float* __restrict__ out_inst)
{
    const int box = blockIdx.x;
    const int c = cls[box];
    if (c == 0) return;

    // b = boxes[:,1:] * 0.25 (exact in fp32); jnp.round = RNE -> rintf
    const float bx0 = boxes[box * 5 + 1] * 0.25f;
    const float by0 = boxes[box * 5 + 2] * 0.25f;
    const float bx1 = boxes[box * 5 + 3] * 0.25f;
    const float by1 = boxes[box * 5 + 4] * 0.25f;
    const int x0 = max((int)floorf(bx0), 0);
    const int y0 = max((int)floorf(by0), 0);
    const int x1 = min((int)(rintf(bx1) + 1.0f), WW);   // clamp to plane
    const int y1 = min((int)(rintf(by1) + 1.0f), HH);
    if (x0 >= x1 || y0 >= y1) return;

    const int mapped = min(c + 10, N_SEG - 1);
    const float* __restrict__ src = seg + (size_t)mapped * HH * WW;
    float* __restrict__ dst = out_inst + (size_t)box * HH * WW;

    for (int y = y0 + blockIdx.y; y < y1; y += gridDim.y) {
        const float* s = src + y * WW;
        float*       d = dst + y * WW;
        for (int x = x0 + (int)threadIdx.x; x < x1; x += 256) {
            d[x] = s[x];
        }
    }
}

extern "C" void kernel_launch(void* const* d_in, const int* in_sizes, int n_in,
                              void* d_out, int out_size, void* d_ws, size_t ws_size,
                              hipStream_t stream) {
    const int*   cls   = (const int*)d_in[0];
    const float* seg   = (const float*)d_in[1];
    const float* boxes = (const float*)d_in[2];
    float*       out   = (float*)d_out;

    // Zero the instance-energy region on the proven 6 TB/s fill path.
    hipMemsetAsync((char*)d_out + STUFF_BYTES, 0, INST_BYTES, stream);

    // Output 0: stuff copy (360448 float4 groups / 4 per thread / 256 per block).
    copy_stuff_kernel<<<COPY_STRIDE / 256, 256, 0, stream>>>(
        (const float4*)seg, (float4*)out);

    // Output 1: fill box interiors only.
    box_fill_kernel<<<dim3(NB, 8), 256, 0, stream>>>(
        cls, seg, boxes, out + (size_t)STUFF_N4 * 4);
}

// Round 3
// 97.110 us; speedup vs baseline: 1.0158x; 1.0158x over previous
//
#include <hip/hip_runtime.h>

// Problem constants (match reference)
#define HH 256
#define WW 512
#define NB 128
#define N_STUFF 11
#define N_SEG 19

constexpr int    W4          = WW / 4;                     // 128 float4 groups per row
constexpr int    STUFF_N4    = N_STUFF * HH * W4;          // 360448 float4 groups
constexpr size_t STUFF_BYTES = (size_t)STUFF_N4 * 16;      // 5,898,240
constexpr size_t INST_BYTES  = (size_t)NB * HH * WW * 4;   // 67,108,864

// Fused work kernel, 64-thread (1-wave) blocks, 1D grid:
//   blocks [0, COPY_BLOCKS)            : stuff-channel copy (4 float4/thread)
//   blocks [COPY_BLOCKS, +NB*HH)       : one (box, row) each; exits fast if
//                                        row outside box or cls==0.
constexpr int COPY_BLOCKS = STUFF_N4 / (64 * 4);           // 1408 (exact)
constexpr int BOX_BLOCKS  = NB * HH;                       // 32768
constexpr int TOTAL_BLOCKS = COPY_BLOCKS + BOX_BLOCKS;     // 34176

__global__ __launch_bounds__(64)
void fused_kernel(const int* __restrict__ cls,
                  const float* __restrict__ seg,
                  const float* __restrict__ boxes,
                  float* __restrict__ out)
{
    const int b = blockIdx.x;
    const int t = threadIdx.x;

    if (b < COPY_BLOCKS) {
        // Output 0: copy first 11 channels. 256 float4 per block.
        const float4* __restrict__ in4  = (const float4*)seg;
        float4* __restrict__       out4 = (float4*)out;
        const int base = b * 256 + t;
        #pragma unroll
        for (int k = 0; k < 4; ++k) {
            out4[base + k * 64] = in4[base + k * 64];
        }
        return;
    }

    // Output 1 interiors: one row of one box per block.
    const int bb  = b - COPY_BLOCKS;
    const int box = bb >> 8;          // / HH
    const int y   = bb & (HH - 1);

    const int c = cls[box];
    if (c == 0) return;

    // b = boxes[:,1:] * 0.25 (exact in fp32); jnp.round = RNE -> rintf
    const float by0 = boxes[box * 5 + 2] * 0.25f;
    const float by1 = boxes[box * 5 + 4] * 0.25f;
    const int y0 = max((int)floorf(by0), 0);
    const int y1 = min((int)(rintf(by1) + 1.0f), HH);
    if (y < y0 || y >= y1) return;

    const float bx0 = boxes[box * 5 + 1] * 0.25f;
    const float bx1 = boxes[box * 5 + 3] * 0.25f;
    const int x0 = max((int)floorf(bx0), 0);
    const int x1 = min((int)(rintf(bx1) + 1.0f), WW);

    const int mapped = min(c + 10, N_SEG - 1);
    const float* __restrict__ s = seg + ((size_t)mapped * HH + y) * WW;
    float* __restrict__ d = out + (size_t)STUFF_N4 * 4 + ((size_t)box * HH + y) * WW;

    // Row width <= 512, typically ~80: <= 3 independent iterations per lane.
    for (int x = x0 + t; x < x1; x += 64) {
        d[x] = s[x];
    }
}

extern "C" void kernel_launch(void* const* d_in, const int* in_sizes, int n_in,
                              void* d_out, int out_size, void* d_ws, size_t ws_size,
                              hipStream_t stream) {
    const int*   cls   = (const int*)d_in[0];
    const float* seg   = (const float*)d_in[1];
    const float* boxes = (const float*)d_in[2];
    float*       out   = (float*)d_out;

    // Zero the instance-energy region on the proven 6.3 TB/s fill path.
    hipMemsetAsync((char*)d_out + STUFF_BYTES, 0, INST_BYTES, stream);

    // One fused dispatch for stuff copy + box interiors.
    fused_kernel<<<TOTAL_BLOCKS, 64, 0, stream>>>(cls, seg, boxes, out);
}

// Round 4
// 89.191 us; speedup vs baseline: 1.1060x; 1.0888x over previous
//
#include <hip/hip_runtime.h>

// Problem constants (match reference)
#define HH 256
#define WW 512
#define NB 128
#define N_STUFF 11
#define N_SEG 19

constexpr int W4       = WW / 4;                  // 128 float4 groups per row
constexpr int STUFF_N4 = N_STUFF * HH * W4;       // 360448 float4 groups
constexpr int BOX_N4   = HH * W4;                 // 32768 groups per box plane

// One dispatch. 256-thread blocks, 4 float4 groups per thread (stride 256):
//   blocks [0, STUFF_BLOCKS)  : copy first 11 channels (output 0)
//   blocks [STUFF_BLOCKS, +NB*32) : instance planes, 8 rows per block (output 1)
constexpr int STUFF_BLOCKS = STUFF_N4 / 1024;     // 352 (exact)
constexpr int INST_BLOCKS  = NB * BOX_N4 / 1024;  // 4096
constexpr int TOTAL_BLOCKS = STUFF_BLOCKS + INST_BLOCKS;  // 4448

__global__ __launch_bounds__(256)
void SegTerm_kernel(const int* __restrict__ cls,
                    const float4* __restrict__ seg4,
                    const float* __restrict__ boxes,
                    float4* __restrict__ out4)
{
    const int blk = blockIdx.x;
    const int t   = threadIdx.x;

    if (blk < STUFF_BLOCKS) {
        // Output 0: straight copy, 4 independent float4 per thread.
        const int base = blk * 1024 + t;
        #pragma unroll
        for (int k = 0; k < 4; ++k)
            out4[base + k * 256] = seg4[base + k * 256];
        return;
    }

    // Output 1: one block covers 8 rows of one box's plane.
    const int b2          = blk - STUFF_BLOCKS;
    const int box         = b2 >> 5;              // 32 blocks per box
    const int base_in_box = (b2 & 31) * 1024;     // group index within plane
    float4* __restrict__ dst = out4 + STUFF_N4 + (size_t)box * BOX_N4;

    const float4 zero = make_float4(0.f, 0.f, 0.f, 0.f);
    const int c = cls[box];                       // block-uniform (scalar)

    if (c == 0) {
        #pragma unroll
        for (int k = 0; k < 4; ++k)
            dst[base_in_box + k * 256 + t] = zero;
        return;
    }

    // b = boxes[:,1:] * 0.25 (exact in fp32); jnp.round = RNE -> rintf
    const float bx0 = boxes[box * 5 + 1] * 0.25f;
    const float by0 = boxes[box * 5 + 2] * 0.25f;
    const float bx1 = boxes[box * 5 + 3] * 0.25f;
    const float by1 = boxes[box * 5 + 4] * 0.25f;
    const int x0 = (int)floorf(bx0);
    const int y0 = (int)floorf(by0);
    const int x1 = (int)(rintf(bx1) + 1.0f);
    const int y1 = (int)(rintf(by1) + 1.0f);

    const int mapped = min(c + 10, N_SEG - 1);
    const float4* __restrict__ src = seg4 + (size_t)mapped * BOX_N4;

    #pragma unroll
    for (int k = 0; k < 4; ++k) {
        const int gi = base_in_box + k * 256 + t;
        const int y  = gi >> 7;                   // row within plane
        const int xg = gi & (W4 - 1);
        const int x  = xg << 2;

        float4 v = zero;
        if (y >= y0 && y < y1) {
            if (x >= x0 && x + 3 < x1) {
                v = src[(y << 7) + xg];           // fully-interior: aligned 16B
            } else if (x + 3 >= x0 && x < x1) {
                const float* s = (const float*)(src + (y << 7)) + x;
                const float e0 = (x     >= x0 && x     < x1) ? s[0] : 0.f;
                const float e1 = (x + 1 >= x0 && x + 1 < x1) ? s[1] : 0.f;
                const float e2 = (x + 2 >= x0 && x + 2 < x1) ? s[2] : 0.f;
                const float e3 = (x + 3 >= x0 && x + 3 < x1) ? s[3] : 0.f;
                v = make_float4(e0, e1, e2, e3);
            }
        }
        dst[gi] = v;
    }
}

extern "C" void kernel_launch(void* const* d_in, const int* in_sizes, int n_in,
                              void* d_out, int out_size, void* d_ws, size_t ws_size,
                              hipStream_t stream) {
    const int*    cls   = (const int*)d_in[0];
    const float4* seg4  = (const float4*)d_in[1];
    const float*  boxes = (const float*)d_in[2];
    float4*       out4  = (float4*)d_out;

    SegTerm_kernel<<<TOTAL_BLOCKS, 256, 0, stream>>>(cls, seg4, boxes, out4);
}